// Round 2
// baseline (437.314 us; speedup 1.0000x reference)
//
#include <hip/hip_runtime.h>

// Problem: B=2048, C=16, S=2000, fp32.
// Reference collapses: softmax rows sum to 1 over m, so
// einsum('bcs,bcm->bcs', x, score) == x exactly. The kernel is therefore
// out = LN_c(Wp @ x[b,:,s] + bp) * gp + hp, a pure streaming op:
// 262 MB in + 262 MB out -> ~83 us roofline @ 6.3 TB/s achievable.
//
// R2 changes vs R1 (435.5 us total; kernel portion ~111 us -- rocprof shows
// the timed region also contains ~2x162us harness poison-fills, and our
// kernel is absent from top-5 dispatches => its dispatch < 160 us):
//  1. Full-occupancy push: __launch_bounds__(256, 8) forces VGPR <= 64
//     -> 8 waves/SIMD (was ~5). All pipes have headroom (VALU ~22% duty),
//     so the 75%-of-BW residual is latency smoothness -> more waves.
//  2. x loaded in two 8-channel halves so only 8 f32x2 xv regs are live
//     at once (peak live ~60 VGPR instead of ~90). The second half's loads
//     overlap the first half's FMAs.
//  3. Weights read as f32x4 LDS broadcasts (64 ds_read_b128 per thread
//     instead of 256 ds_read_b32) -- fewer issue slots, fewer waits.

#define NC 16          // channels
#define NS 2000        // sequence
#define SV2 (NS / 2)   // 1000 float2 per (b,c) row
#define EPS 1e-5f
#define BLK 256

typedef float f32x2 __attribute__((ext_vector_type(2)));
typedef float f32x4 __attribute__((ext_vector_type(4)));

__global__ __launch_bounds__(BLK, 8) void chanattn_fused(
    const float* __restrict__ x,
    const float* __restrict__ Wp,
    const float* __restrict__ bp,
    const float* __restrict__ gp,
    const float* __restrict__ hp,
    float* __restrict__ out,
    unsigned total)        // B * SV2
{
    // Params in LDS, W transposed: sW[cp][c] = Wp[c][cp], c contiguous so a
    // f32x4 read grabs 4 output channels for one input channel. All lanes
    // read the same address -> LDS broadcast, conflict-free.
    __shared__ f32x4 sW4[NC * NC / 4];
    __shared__ float sb[NC], sg[NC], sh[NC];
    const int tid = threadIdx.x;
    if (tid < NC * NC) ((float*)sW4)[(tid & (NC - 1)) * NC + (tid >> 4)] = Wp[tid];
    if (tid < NC) { sb[tid] = bp[tid]; sg[tid] = gp[tid]; sh[tid] = hp[tid]; }
    __syncthreads();

    const unsigned t = blockIdx.x * BLK + tid;
    if (t >= total) return;
    const unsigned b  = t / SV2;       // const-division -> magic mul
    const unsigned s2 = t - b * SV2;

    const f32x2* __restrict__ px = (const f32x2*)x   + (size_t)b * (NC * SV2) + s2;
    f32x2*       __restrict__ po = (f32x2*)out       + (size_t)b * (NC * SV2) + s2;

    // y[c] = bp[c] + sum_cp Wp[c][cp] * x[cp]   (2 positions at once)
    f32x2 y[NC];
#pragma unroll
    for (int c = 0; c < NC; ++c) {
        const float bb = sb[c];
        y[c].x = bb; y[c].y = bb;
    }

    // ---- first 8 input channels: load, then FMA (8 loads in flight) ----
    f32x2 xv[8];
#pragma unroll
    for (int cp = 0; cp < 8; ++cp)
        xv[cp] = __builtin_nontemporal_load(&px[cp * SV2]);
#pragma unroll
    for (int cp = 0; cp < 8; ++cp) {
        const f32x2 xc = xv[cp];
#pragma unroll
        for (int k = 0; k < 4; ++k) {
            const f32x4 w = sW4[cp * 4 + k];
            y[4 * k + 0].x = fmaf(w.x, xc.x, y[4 * k + 0].x);
            y[4 * k + 0].y = fmaf(w.x, xc.y, y[4 * k + 0].y);
            y[4 * k + 1].x = fmaf(w.y, xc.x, y[4 * k + 1].x);
            y[4 * k + 1].y = fmaf(w.y, xc.y, y[4 * k + 1].y);
            y[4 * k + 2].x = fmaf(w.z, xc.x, y[4 * k + 2].x);
            y[4 * k + 2].y = fmaf(w.z, xc.y, y[4 * k + 2].y);
            y[4 * k + 3].x = fmaf(w.w, xc.x, y[4 * k + 3].x);
            y[4 * k + 3].y = fmaf(w.w, xc.y, y[4 * k + 3].y);
        }
    }

    // ---- second 8 input channels: reuse xv regs (loads overlap FMAs) ----
#pragma unroll
    for (int cp = 8; cp < NC; ++cp)
        xv[cp - 8] = __builtin_nontemporal_load(&px[cp * SV2]);
#pragma unroll
    for (int cp = 8; cp < NC; ++cp) {
        const f32x2 xc = xv[cp - 8];
#pragma unroll
        for (int k = 0; k < 4; ++k) {
            const f32x4 w = sW4[cp * 4 + k];
            y[4 * k + 0].x = fmaf(w.x, xc.x, y[4 * k + 0].x);
            y[4 * k + 0].y = fmaf(w.x, xc.y, y[4 * k + 0].y);
            y[4 * k + 1].x = fmaf(w.y, xc.x, y[4 * k + 1].x);
            y[4 * k + 1].y = fmaf(w.y, xc.y, y[4 * k + 1].y);
            y[4 * k + 2].x = fmaf(w.z, xc.x, y[4 * k + 2].x);
            y[4 * k + 2].y = fmaf(w.z, xc.y, y[4 * k + 2].y);
            y[4 * k + 3].x = fmaf(w.w, xc.x, y[4 * k + 3].x);
            y[4 * k + 3].y = fmaf(w.w, xc.y, y[4 * k + 3].y);
        }
    }

    // LayerNorm over the 16 channels, per position (two-pass, in registers).
    float sx = 0.f, sy = 0.f;
#pragma unroll
    for (int c = 0; c < NC; ++c) { sx += y[c].x; sy += y[c].y; }
    const float inv = 1.0f / NC;
    const float mux = sx * inv, muy = sy * inv;

    float vx = 0.f, vy = 0.f;
#pragma unroll
    for (int c = 0; c < NC; ++c) {
        const float dx = y[c].x - mux, dy = y[c].y - muy;
        vx = fmaf(dx, dx, vx);
        vy = fmaf(dy, dy, vy);
    }
    const float rx = rsqrtf(vx * inv + EPS);
    const float ry = rsqrtf(vy * inv + EPS);

#pragma unroll
    for (int c = 0; c < NC; ++c) {
        const float g = sg[c], h = sh[c];
        f32x2 o;
        o.x = fmaf((y[c].x - mux) * rx, g, h);
        o.y = fmaf((y[c].y - muy) * ry, g, h);
        __builtin_nontemporal_store(o, &po[c * SV2]);
    }
}

extern "C" void kernel_launch(void* const* d_in, const int* in_sizes, int n_in,
                              void* d_out, int out_size, void* d_ws, size_t ws_size,
                              hipStream_t stream) {
    // setup_inputs order: x, Wq, bq, gq, hq, Wk, bk, gk, hk, Wp, bp, gp, hp
    const float* x  = (const float*)d_in[0];
    const float* Wp = (const float*)d_in[9];
    const float* bp = (const float*)d_in[10];
    const float* gp = (const float*)d_in[11];
    const float* hp = (const float*)d_in[12];
    float* out = (float*)d_out;

    const unsigned B = (unsigned)(in_sizes[0] / (NC * NS));  // 2048
    const unsigned total = B * SV2;                           // 2,048,000
    const unsigned grid = (total + BLK - 1) / BLK;            // 8000
    chanattn_fused<<<grid, BLK, 0, stream>>>(x, Wp, bp, gp, hp, out, total);
}